// Round 11
// baseline (308.877 us; speedup 1.0000x reference)
//
#include <hip/hip_runtime.h>
#include <math.h>

constexpr int cB = 2, cC = 64, cH = 48, cW = 48, cL = 48 * 48;
constexpr int cBR = 128, cDI = 128, cNS = 16, cRK = 4, cK = 4;
constexpr float cEPS = 1e-5f;
constexpr int NCH = 64;          // scan chunks
constexpr int CHL = cL / NCH;    // 36 positions per chunk
constexpr int KTOT = 5824;       // 9*640 conv + 64 shortcut

typedef unsigned short u16;
typedef unsigned int u32;
typedef short s16x8 __attribute__((ext_vector_type(8)));
typedef float f32x4 __attribute__((ext_vector_type(4)));

__device__ __forceinline__ float bnrelu(float v, float g, float b) {
    float y = v * (g * rsqrtf(1.0f + cEPS)) + b;
    return y > 0.f ? y : 0.f;
}
__device__ __forceinline__ float silu(float v) {
    return v / (1.f + expf(-v));
}
__device__ __forceinline__ u16 f2bf(float f) {
    u32 u = __float_as_uint(f);
    u = (u + 0x7fffu + ((u >> 16) & 1u)) >> 16;
    return (u16)u;
}
__device__ __forceinline__ s16x8 cvt8(const float* p) {
    s16x8 r;
#pragma unroll
    for (int i = 0; i < 8; i++) r[i] = (short)f2bf(p[i]);
    return r;
}
// sum over each aligned 16-lane row via DPP (full-rate VALU, no DS pipe)
__device__ __forceinline__ float row_sum16(float v) {
    v += __int_as_float(__builtin_amdgcn_update_dpp(0, __float_as_int(v), 0xB1, 0xF, 0xF, true));  // quad xor1
    v += __int_as_float(__builtin_amdgcn_update_dpp(0, __float_as_int(v), 0x4E, 0xF, 0xF, true));  // quad xor2
    v += __int_as_float(__builtin_amdgcn_update_dpp(0, __float_as_int(v), 0x124, 0xF, 0xF, true)); // row_ror:4
    v += __int_as_float(__builtin_amdgcn_update_dpp(0, __float_as_int(v), 0x128, 0xF, 0xF, true)); // row_ror:8
    return v;
}

// ------- fused setup: pools (blk 0..1639) | weight prep (blk 1640..3295) -------
__global__ void __launch_bounds__(256) k_setup(
    const float* __restrict__ x, float* __restrict__ pool3, float* __restrict__ pool5,
    float* __restrict__ pool9, float* __restrict__ gmean,
    const float* __restrict__ cw, const float* __restrict__ scw,
    const float* __restrict__ s0w, const float* __restrict__ s1w,
    const float* __restrict__ ipw, const float* __restrict__ xpw,
    u16* __restrict__ w8, u16* __restrict__ wcat,
    u16* __restrict__ ipk, u16* __restrict__ xpk) {
    __shared__ float sm[4];
    int blk = blockIdx.x;
    int t = threadIdx.x;
    if (blk < 1152) {
        int idx = blk * 256 + t;
        int w = idx % cW, h = (idx / cW) % cH, bc = idx / cL;
        const float* p = x + bc * cL;
        float s = 0.f;
        for (int dh = -1; dh <= 1; dh++) {
            int hh = h + dh; if (hh < 0 || hh >= cH) continue;
            for (int dw = -1; dw <= 1; dw++) {
                int ww = w + dw; if (ww < 0 || ww >= cW) continue;
                s += p[hh * cW + ww];
            }
        }
        pool3[idx] = s * (1.f / 9.f);
    } else if (blk < 1440) {
        int idx = (blk - 1152) * 256 + t;   // 5x5 s2 p2 -> 24x24
        int w = idx % 24, h = (idx / 24) % 24, bc = idx / 576;
        const float* p = x + bc * cL;
        float s = 0.f;
        for (int kh = 0; kh < 5; kh++) {
            int hh = h * 2 - 2 + kh; if (hh < 0 || hh >= cH) continue;
            for (int kw = 0; kw < 5; kw++) {
                int ww = w * 2 - 2 + kw; if (ww < 0 || ww >= cW) continue;
                s += p[hh * cW + ww];
            }
        }
        pool5[idx] = s * (1.f / 25.f);
    } else if (blk < 1512) {
        int idx = (blk - 1440) * 256 + t;   // 9x9 s4 p4 -> 12x12
        int w = idx % 12, h = (idx / 12) % 12, bc = idx / 144;
        const float* p = x + bc * cL;
        float s = 0.f;
        for (int kh = 0; kh < 9; kh++) {
            int hh = h * 4 - 4 + kh; if (hh < 0 || hh >= cH) continue;
            for (int kw = 0; kw < 9; kw++) {
                int ww = w * 4 - 4 + kw; if (ww < 0 || ww >= cW) continue;
                s += p[hh * cW + ww];
            }
        }
        pool9[idx] = s * (1.f / 81.f);
    } else if (blk < 1640) {
        int bc = blk - 1512;
        const float* p = x + bc * cL;
        float s = 0.f;
        for (int i = t; i < cL; i += 256) s += p[i];
        for (int m = 32; m > 0; m >>= 1) s += __shfl_down(s, m);
        if ((t & 63) == 0) sm[t >> 6] = s;
        __syncthreads();
        if (t == 0) gmean[bc] = (sm[0] + sm[1] + sm[2] + sm[3]) * (1.f / cL);
    } else {
        int pblk = blk - 1640;
        if (pblk < 1456) {
            int idx = pblk * 256 + t;  // < 64*KTOT exactly
            int o = idx / KTOT, kx = idx % KTOT;
            float v;
            if (kx < 5760) { int tap = kx / 640, ch = kx % 640; v = cw[(o * 640 + ch) * 9 + tap]; }
            else v = scw[o * 64 + (kx - 5760)];
            w8[(((size_t)(kx >> 3) * 64) + o) * 8 + (kx & 7)] = f2bf(v);
        } else if (pblk < 1520) {
            int idx = (pblk - 1456) * 256 + t;
            int g = idx >> 13, r = idx & 8191;
            int o = r >> 6, c = r & 63;
            float v = (g ? s1w : s0w)[r];
            int kt = c >> 5, q = (c >> 3) & 3, j = c & 7, nt = o >> 4, ln = o & 15;
            wcat[(size_t)((((g * 2 + kt) * 4 + q) * 8 + nt) * 16 + ln) * 8 + j] = f2bf(v);
        } else if (pblk < 1584) {
            int idx = (pblk - 1520) * 256 + t;
            int o = idx >> 6, c = idx & 63;
            int kt = c >> 5, q = (c >> 3) & 3, j = c & 7, nt = o >> 4, ln = o & 15;
            ipk[(size_t)(((kt * 4 + q) * 16 + nt) * 16 + ln) * 8 + j] = f2bf(ipw[idx]);
        } else {
            int idx = (pblk - 1584) * 256 + t;
            int o = idx >> 7, d = idx & 127;
            int kt = d >> 5, q = (d >> 3) & 3, j = d & 7, nt = o >> 4, ln = o & 15;
            xpk[(size_t)(((kt * 4 + q) * 9 + nt) * 16 + ln) * 8 + j] = f2bf(xpw[idx]);
        }
    }
}

// ------- fused bn_relu + 1x1 conv (64->128), channel-LAST outputs -------
__global__ void __launch_bounds__(128) k_c1all(const float* __restrict__ pool5, const float* __restrict__ pool9,
                                               const float* __restrict__ gm,
                                               const float* __restrict__ s2g, const float* __restrict__ s2b,
                                               const float* __restrict__ s2w,
                                               const float* __restrict__ s3g, const float* __restrict__ s3b,
                                               const float* __restrict__ s3w,
                                               const float* __restrict__ s4g, const float* __restrict__ s4b,
                                               const float* __restrict__ s4w,
                                               float* __restrict__ c2cl, float* __restrict__ c3cl,
                                               float* __restrict__ c4) {
    int pos = blockIdx.x;
    const float *in, *g, *bb, *w;
    float* outp;
    int HW, b, pp;
    if (pos < cB * 576) { b = pos / 576; pp = pos % 576; in = pool5; g = s2g; bb = s2b; w = s2w; HW = 576; outp = c2cl + ((size_t)b * 576 + pp) * 128; }
    else if (pos < cB * 576 + cB * 144) { int r = pos - cB * 576; b = r / 144; pp = r % 144; in = pool9; g = s3g; bb = s3b; w = s3w; HW = 144; outp = c3cl + ((size_t)b * 144 + pp) * 128; }
    else { b = pos - cB * 576 - cB * 144; pp = 0; in = gm; g = s4g; bb = s4b; w = s4w; HW = 1; outp = c4 + (size_t)b * 128; }
    __shared__ float v[64];
    int t = threadIdx.x;
    if (t < 64) v[t] = bnrelu(in[(b * 64 + t) * HW + pp], g[t], bb[t]);
    __syncthreads();
    float acc = 0.f;
    const float* wr = w + t * 64;
#pragma unroll 16
    for (int c = 0; c < 64; c++) acc += v[c] * wr[c];
    outp[t] = acc;
}

// ------- cat build: staged loads + MFMA 1x1 convs + INLINE bilinear + fused epilogue -------
__global__ void __launch_bounds__(256) k_cat2(
    const float* __restrict__ x, const float* __restrict__ pool3, const float* __restrict__ c4,
    const float* __restrict__ s0g, const float* __restrict__ s0b,
    const float* __restrict__ s1g, const float* __restrict__ s1b,
    const float* __restrict__ scg, const float* __restrict__ scb,
    const float* __restrict__ cg, const float* __restrict__ cbb,
    const u16* __restrict__ wcat, const float* __restrict__ c2cl, const float* __restrict__ c3cl,
    u16* __restrict__ catbf, u16* __restrict__ xbf) {
    int blk = blockIdx.x;
    int b = blk / 144;
    int l0 = (blk % 144) * 16;
    int t = threadIdx.x;
    __shared__ float axv[16][68];
    __shared__ float ap3[16][68];
    __shared__ u16 axc[16][66];
    int pc = t >> 4, p = t & 15;
#pragma unroll
    for (int i = 0; i < 4; i++) {
        int c = i * 16 + pc;
        float xraw = x[(size_t)(b * 64 + c) * cL + l0 + p];
        float p3raw = pool3[(size_t)(b * 64 + c) * cL + l0 + p];
        axv[p][c] = bnrelu(xraw, s0g[c], s0b[c]);
        ap3[p][c] = bnrelu(p3raw, s1g[c], s1b[c]);
        axc[p][c] = f2bf(bnrelu(xraw, scg[c], scb[c]));
    }
    __syncthreads();
#pragma unroll
    for (int i = 0; i < 4; i++) {
        int idx = i * 256 + t;
        int pp = idx >> 6, cc = idx & 63;
        xbf[((size_t)b * cL + l0 + pp) * 64 + cc] = axc[pp][cc];
    }
    int wv = t >> 6, lane = t & 63, ln = lane & 15, q = lane >> 4;
    f32x4 ax[2] = {};
    f32x4 ay[2] = {};
#pragma unroll
    for (int kt = 0; kt < 2; kt++) {
        s16x8 a0 = cvt8(&axv[ln][kt * 32 + q * 8]);
        s16x8 a1 = cvt8(&ap3[ln][kt * 32 + q * 8]);
#pragma unroll
        for (int jj = 0; jj < 2; jj++) {
            int nt = wv * 2 + jj;
            s16x8 b0 = *(const s16x8*)(wcat + (size_t)((((0 * 2 + kt) * 4 + q) * 8 + nt) * 16 + ln) * 8);
            s16x8 b1 = *(const s16x8*)(wcat + (size_t)((((1 * 2 + kt) * 4 + q) * 8 + nt) * 16 + ln) * 8);
            ax[jj] = __builtin_amdgcn_mfma_f32_16x16x32_bf16(a0, b0, ax[jj], 0, 0, 0);
            ay[jj] = __builtin_amdgcn_mfma_f32_16x16x32_bf16(a1, b1, ay[jj], 0, 0, 0);
        }
    }
    // bilinear setup (row uniform per block)
    int hrow = l0 / cW, w0g = l0 % cW;
    float sy2 = hrow * 0.5f - 0.25f;
    float fy2 = floorf(sy2); int iy2 = (int)fy2; float ay2 = sy2 - fy2;
    int y20 = min(max(iy2, 0), 23), y21 = min(max(iy2 + 1, 0), 23);
    float sy3 = hrow * 0.25f - 0.375f;
    float fy3 = floorf(sy3); int iy3 = (int)fy3; float ay3 = sy3 - fy3;
    int y30 = min(max(iy3, 0), 11), y31 = min(max(iy3 + 1, 0), 11);
    const float* c2b = c2cl + (size_t)b * 576 * 128;
    const float* c3b = c3cl + (size_t)b * 144 * 128;
#pragma unroll
    for (int r = 0; r < 4; r++) {
        int pp = q * 4 + r;
        int wq = w0g + pp;
        float sx2 = wq * 0.5f - 0.25f;
        float fx2 = floorf(sx2); int ix2 = (int)fx2; float ax2 = sx2 - fx2;
        int x20 = min(max(ix2, 0), 23), x21 = min(max(ix2 + 1, 0), 23);
        float sx3 = wq * 0.25f - 0.375f;
        float fx3 = floorf(sx3); int ix3 = (int)fx3; float ax3 = sx3 - fx3;
        int x30 = min(max(ix3, 0), 11), x31 = min(max(ix3 + 1, 0), 11);
#pragma unroll
        for (int jj = 0; jj < 2; jj++) {
            int ch = (wv * 2 + jj) * 16 + ln;
            float v00 = c2b[(y20 * 24 + x20) * 128 + ch], v01 = c2b[(y20 * 24 + x21) * 128 + ch];
            float v10 = c2b[(y21 * 24 + x20) * 128 + ch], v11 = c2b[(y21 * 24 + x21) * 128 + ch];
            float t0 = v00 + (v01 - v00) * ax2, t1 = v10 + (v11 - v10) * ax2;
            float u2v = t0 + (t1 - t0) * ay2;
            float w00 = c3b[(y30 * 12 + x30) * 128 + ch], w01 = c3b[(y30 * 12 + x31) * 128 + ch];
            float w10 = c3b[(y31 * 12 + x30) * 128 + ch], w11 = c3b[(y31 * 12 + x31) * 128 + ch];
            float s0_ = w00 + (w01 - w00) * ax3, s1_ = w10 + (w11 - w10) * ax3;
            float u3v = s0_ + (s1_ - s0_) * ay3;
            float x0 = ax[jj][r];
            float y1 = ay[jj][r] + x0;
            float y2 = x0 + u2v;
            float y3 = x0 + u3v;
            float y4 = x0 + c4[b * 128 + ch];
            u16* base = catbf + ((size_t)b * cL + l0 + pp) * 640;
            base[ch]       = f2bf(bnrelu(x0, cg[ch],       cbb[ch]));
            base[128 + ch] = f2bf(bnrelu(y1, cg[128 + ch], cbb[128 + ch]));
            base[256 + ch] = f2bf(bnrelu(y2, cg[256 + ch], cbb[256 + ch]));
            base[384 + ch] = f2bf(bnrelu(y3, cg[384 + ch], cbb[384 + ch]));
            base[512 + ch] = f2bf(bnrelu(y4, cg[512 + ch], cbb[512 + ch]));
        }
    }
}

// ------- comp 3x3 conv + shortcut: split-K MFMA GEMM -------
__global__ void __launch_bounds__(64) k_comp(const u16* __restrict__ catbf,
                                             const u16* __restrict__ xbf,
                                             const u16* __restrict__ w8,
                                             float* __restrict__ part) {
    int blk = blockIdx.x;
    int slice = blk % 9;
    int pxt = blk / 9;
    int pix0 = pxt * 16;
    int b = pix0 / cL;
    int lane = threadIdx.x;
    int ln = lane & 15, q = lane >> 4;
    int la = (pix0 + ln) - b * cL;
    int h = la / cW, w = la % cW;
    int kh = slice / 3 - 1, kw = slice % 3 - 1;
    int hh = h + kh, ww = w + kw;
    bool ok = (hh >= 0) && (hh < cH) && (ww >= 0) && (ww < cW);
    const u16* ap = catbf + ((size_t)b * cL + hh * cW + ww) * 640 + q * 8;
    f32x4 acc[4] = {};
    int kb = slice * 640;
#pragma unroll 4
    for (int cc = 0; cc < 20; cc++) {
        s16x8 av;
        if (ok) av = *(const s16x8*)(ap + cc * 32);
        else av = s16x8{0, 0, 0, 0, 0, 0, 0, 0};
        const u16* wrow = w8 + (((size_t)((kb + cc * 32) >> 3) + q) * 64) * 8;
#pragma unroll
        for (int j = 0; j < 4; j++) {
            s16x8 bv = *(const s16x8*)(wrow + (size_t)(j * 16 + ln) * 8);
            acc[j] = __builtin_amdgcn_mfma_f32_16x16x32_bf16(av, bv, acc[j], 0, 0, 0);
        }
    }
    if (slice == 4) {
        const u16* xp = xbf + (size_t)(pix0 + ln) * 64 + q * 8;
#pragma unroll
        for (int cc = 0; cc < 2; cc++) {
            s16x8 av = *(const s16x8*)(xp + cc * 32);
            const u16* wrow = w8 + (((size_t)((5760 + cc * 32) >> 3) + q) * 64) * 8;
#pragma unroll
            for (int j = 0; j < 4; j++) {
                s16x8 bv = *(const s16x8*)(wrow + (size_t)(j * 16 + ln) * 8);
                acc[j] = __builtin_amdgcn_mfma_f32_16x16x32_bf16(av, bv, acc[j], 0, 0, 0);
            }
        }
    }
    float* pb = part + ((size_t)slice * (cB * cL) + pix0) * 64;
#pragma unroll
    for (int j = 0; j < 4; j++) {
#pragma unroll
        for (int r = 0; r < 4; r++) {
            pb[(size_t)(q * 4 + r) * 64 + j * 16 + ln] = acc[j][r];
        }
    }
}

// ------- fused split-K reduce + in_proj MFMA: part -> xc (B,L,128), z (B,L,128) -------
__global__ void __launch_bounds__(256) k_ip(const float* __restrict__ part, const u16* __restrict__ ipk,
                                            float* __restrict__ xc, float* __restrict__ z) {
    int px0 = blockIdx.x * 16;
    int t = threadIdx.x;
    __shared__ float pv[16][68];
#pragma unroll
    for (int i = 0; i < 4; i++) {
        int idx = i * 256 + t;
        int p = idx >> 6, c = idx & 63;
        float s = 0.f;
#pragma unroll
        for (int sl = 0; sl < 9; sl++)
            s += part[((size_t)sl * (cB * cL) + px0 + p) * 64 + c];
        pv[p][c] = s;
    }
    __syncthreads();
    int wv = t >> 6, lane = t & 63, ln = lane & 15, q = lane >> 4;
    f32x4 acc[4] = {};
#pragma unroll
    for (int kt = 0; kt < 2; kt++) {
        s16x8 a = cvt8(&pv[ln][kt * 32 + q * 8]);
#pragma unroll
        for (int jn = 0; jn < 4; jn++) {
            int nt = wv * 4 + jn;
            s16x8 bfr = *(const s16x8*)(ipk + (size_t)(((kt * 4 + q) * 16 + nt) * 16 + ln) * 8);
            acc[jn] = __builtin_amdgcn_mfma_f32_16x16x32_bf16(a, bfr, acc[jn], 0, 0, 0);
        }
    }
#pragma unroll
    for (int jn = 0; jn < 4; jn++) {
        int o = (wv * 4 + jn) * 16 + ln;
#pragma unroll
        for (int r = 0; r < 4; r++) {
            int p = q * 4 + r;
            if (o < 128) xc[((size_t)px0 + p) * 128 + o] = acc[jn][r];
            else         z[((size_t)px0 + p) * 128 + (o - 128)] = acc[jn][r];
        }
    }
}

// ------- depthwise 3x3 + bias + silu; channel-last in/out -------
__global__ void k_dw(const float* __restrict__ xc, const float* __restrict__ dww,
                     const float* __restrict__ dwb, float* __restrict__ xca) {
    int idx = blockIdx.x * 256 + threadIdx.x;
    if (idx >= cB * cL * cDI) return;
    int d = idx & 127;
    int rest = idx >> 7;
    int l = rest % cL, b = rest / cL;
    int h = l / cW, w = l % cW;
    const float* base = xc + (size_t)b * cL * 128 + d;
    float acc = dwb[d];
    const float* kw = dww + d * 9;
    for (int i = 0; i < 3; i++) {
        int hh = h + i - 1; if (hh < 0 || hh >= cH) continue;
        for (int j = 0; j < 3; j++) {
            int ww = w + j - 1; if (ww < 0 || ww >= cW) continue;
            acc += base[(size_t)(hh * cW + ww) * 128] * kw[i * 3 + j];
        }
    }
    xca[idx] = silu(acc);
}

// ------- spatial x_dbl via MFMA + fused softplus; outputs in SPATIAL order -------
// bc layout: (bk, p, 32) with slots interleaved (B[n] at 2n, C[n] at 2n+1)
__global__ void __launch_bounds__(256) k_xdbl4(const float* __restrict__ xca, const u16* __restrict__ xpk,
                                               const float* __restrict__ dtw, const float* __restrict__ dtb,
                                               float* __restrict__ bc, float* __restrict__ delta) {
    int blk = blockIdx.x;
    int b = blk / 144;
    int l0 = (blk % 144) * 16;
    int t = threadIdx.x;
    __shared__ float av[16][132];
    __shared__ float Dt[16][148];
#pragma unroll
    for (int i = 0; i < 8; i++) {
        int id = i * 256 + t;
        int d = id & 127, p = id >> 7;
        av[p][d] = xca[((size_t)b * cL + l0 + p) * 128 + d];
    }
    __syncthreads();
    int wv = t >> 6, lane = t & 63, ln = lane & 15, q = lane >> 4;
    int nmax = (wv == 0) ? 3 : 2;
    f32x4 acc[3] = {};
#pragma unroll
    for (int kt = 0; kt < 4; kt++) {
        s16x8 a = cvt8(&av[ln][kt * 32 + q * 8]);
        for (int i = 0; i < nmax; i++) {
            int nt = (i == 2) ? 8 : wv + i * 4;
            s16x8 bfr = *(const s16x8*)(xpk + (size_t)(((kt * 4 + q) * 9 + nt) * 16 + ln) * 8);
            acc[i] = __builtin_amdgcn_mfma_f32_16x16x32_bf16(a, bfr, acc[i], 0, 0, 0);
        }
    }
    for (int i = 0; i < nmax; i++) {
        int nt = (i == 2) ? 8 : wv + i * 4;
#pragma unroll
        for (int r = 0; r < 4; r++)
            Dt[q * 4 + r][nt * 16 + ln] = acc[i][r];
    }
    __syncthreads();
    // bc out: (bk, p, 32) interleaved pairs (B,C)
#pragma unroll
    for (int i = 0; i < 8; i++) {
        int id = i * 256 + t;
        int cc = id & 31, kk = (id >> 5) & 3, p = id >> 7;
        int slot = (cc < 16) ? (cc * 2) : ((cc - 16) * 2 + 1);
        bc[((size_t)(b * 4 + kk) * cL + l0 + p) * 32 + slot] = Dt[p][kk * 36 + 4 + cc];
    }
    // delta = softplus(dtb + dts . dtw): (bk, p, 128), coalesced
    for (int i = 0; i < 32; i++) {
        int id = i * 256 + t;
        int d = id & 127, kk = (id >> 7) & 3, p = id >> 9;
        const float* wd = dtw + (size_t)(kk * 128 + d) * 4;
        float pre = dtb[kk * 128 + d] + wd[0] * Dt[p][kk * 36] + wd[1] * Dt[p][kk * 36 + 1]
                  + wd[2] * Dt[p][kk * 36 + 2] + wd[3] * Dt[p][kk * 36 + 3];
        float dl = pre > 20.f ? pre : log1pf(expf(pre));
        delta[((size_t)(b * 4 + kk) * cL + l0 + p) * 128 + d] = dl;
    }
}

// xs index mapping: offset into the (H*W) plane for direction k at scan pos l
__device__ __forceinline__ int xs_index(int k, int l) {
    int lp = (k & 2) ? (cL - 1 - l) : l;
    if (k & 1) { int w = lp / cH, h = lp % cH; return h * cW + w; }
    return lp;
}

// ------- scan pass 1: spatial-order inputs, incremental permuted offset -------
__global__ void __launch_bounds__(256) k_scan1(const float* __restrict__ delta, const float* __restrict__ xca,
                                               const float* __restrict__ bc, const float* __restrict__ Alogs,
                                               float* __restrict__ Pend, float* __restrict__ hend) {
    int blk = blockIdx.x;            // ((bk*8+dgq)*NCH + c)
    int c = blk & 63;
    if (c == NCH - 1) return;        // last chunk's P/h never consumed
    int g = blk >> 6;
    int dgq = g & 7, bk = g >> 3;
    int k = bk & 3, b = bk >> 2;
    int t = threadIdx.x;
    int n = t & 15;
    int d = dgq * 16 + (t >> 4);
    float A = -expf(Alogs[(k * 128 + d) * 16 + n]);
    const float* dp = delta + (size_t)bk * cL * 128 + d;
    const float* xp = xca + (size_t)b * cL * 128 + d;
    const float* bp = bc + (size_t)bk * cL * 32 + n * 2;
    int off = xs_index(k, c * CHL);
    int step = (k == 0) ? 1 : (k == 1) ? cW : (k == 2) ? -1 : -cW;
    float P = 1.f, h = 0.f;
#pragma unroll 4
    for (int i = 0; i < CHL; i++) {
        float dl = dp[(size_t)off * 128];
        float2 bcv = *(const float2*)(bp + (size_t)off * 32);
        float a = expf(dl * A);
        h = a * h + dl * xp[(size_t)off * 128] * bcv.x;
        P *= a;
        off += step;
        if (off >= cL) off -= (cL - 1);
        else if (off < 0) off += (cL - 1);
    }
    Pend[(size_t)blk * 256 + t] = P;
    hend[(size_t)blk * 256 + t] = h;
}

// ------- scan pass 2: sequential combine; writes h_in in-place into hend -------
__global__ void __launch_bounds__(256) k_scan2(const float* __restrict__ Pend, float* __restrict__ hend) {
    int id = blockIdx.x * 256 + threadIdx.x;  // 16384 total
    int t = id & 255;
    int g = id >> 8;
    float h = 0.f;
    for (int c = 0; c < NCH; c++) {
        size_t idx = ((size_t)g * NCH + c) * 256 + t;
        float tmp = hend[idx];
        float Pv = Pend[idx];
        hend[idx] = h;
        h = Pv * h + tmp;
    }
}

// ------- scan pass 3: re-scan; y written in SPATIAL order (bk, p, 128) -------
__global__ void __launch_bounds__(256) k_scan3(const float* __restrict__ delta, const float* __restrict__ xca,
                                               const float* __restrict__ bc, const float* __restrict__ Alogs,
                                               const float* __restrict__ Dsv, const float* __restrict__ hinb,
                                               float* __restrict__ y) {
    int blk = blockIdx.x;
    int c = blk & 63;
    int g = blk >> 6;
    int dgq = g & 7, bk = g >> 3;
    int k = bk & 3, b = bk >> 2;
    int t = threadIdx.x;
    int n = t & 15;
    int d = dgq * 16 + (t >> 4);
    float A = -expf(Alogs[(k * 128 + d) * 16 + n]);
    float Dsd = Dsv[k * 128 + d];
    const float* dp = delta + (size_t)bk * cL * 128 + d;
    const float* xp = xca + (size_t)b * cL * 128 + d;
    const float* bp = bc + (size_t)bk * cL * 32 + n * 2;
    float* yb = y + (size_t)bk * cL * 128 + d;
    int off = xs_index(k, c * CHL);
    int step = (k == 0) ? 1 : (k == 1) ? cW : (k == 2) ? -1 : -cW;
    float h = hinb[(size_t)blk * 256 + t];
#pragma unroll 2
    for (int i = 0; i < CHL; i++) {
        float dl = dp[(size_t)off * 128];
        float xv = xp[(size_t)off * 128];
        float2 bcv = *(const float2*)(bp + (size_t)off * 32);
        float a = expf(dl * A);
        h = a * h + dl * xv * bcv.x;
        float contrib = row_sum16(h * bcv.y);
        if (n == 0) yb[(size_t)off * 128] = contrib + xv * Dsd;
        off += step;
        if (off >= cL) off -= (cL - 1);
        else if (off < 0) off += (cL - 1);
    }
}

// ------- fused tail: 4-dir sum + LN + gate + out_proj + MLP + residual -------
__global__ void __launch_bounds__(256) k_tail(const float* __restrict__ y, const float* __restrict__ z,
                                              const float* __restrict__ lng, const float* __restrict__ lnb,
                                              const float* __restrict__ opw,
                                              const float* __restrict__ f1w, const float* __restrict__ f1b,
                                              const float* __restrict__ f2w, const float* __restrict__ f2b,
                                              float* __restrict__ out) {
    int blk = blockIdx.x;
    int b = blk / 144;
    int l0 = (blk % 144) * 16;
    int t = threadIdx.x;
    __shared__ float v[16][132];
    __shared__ float x1s[16][68];
    __shared__ float h1s[16][132];
    __shared__ float mus[16], rss[16];
    const float* yb = y + (size_t)b * 4 * cL * 128;
#pragma unroll
    for (int i = 0; i < 8; i++) {
        int id = i * 256 + t;
        int d = id & 127, p = id >> 7;
        size_t base = (size_t)(l0 + p) * 128 + d;
        v[p][d] = yb[base] + yb[(size_t)cL * 128 + base] + yb[(size_t)2 * cL * 128 + base] + yb[(size_t)3 * cL * 128 + base];
    }
    __syncthreads();
    {
        int p = t >> 4, c8 = (t & 15) * 8;
        float s = 0.f;
#pragma unroll
        for (int j = 0; j < 8; j++) s += v[p][c8 + j];
        s = row_sum16(s);
        float mu = s * (1.f / 128.f);
        float s2 = 0.f;
#pragma unroll
        for (int j = 0; j < 8; j++) { float dv = v[p][c8 + j] - mu; s2 += dv * dv; }
        s2 = row_sum16(s2);
        if ((t & 15) == 0) { mus[p] = mu; rss[p] = rsqrtf(s2 * (1.f / 128.f) + cEPS); }
    }
    __syncthreads();
#pragma unroll
    for (int i = 0; i < 8; i++) {
        int id = i * 256 + t;
        int d = id & 127, p = id >> 7;
        float zz = z[((size_t)b * cL + l0 + p) * 128 + d];
        v[p][d] = ((v[p][d] - mus[p]) * rss[p] * lng[d] + lnb[d]) * silu(zz);
    }
    __syncthreads();
#pragma unroll
    for (int i = 0; i < 4; i++) {
        int id = i * 256 + t;
        int p = id & 15, o = id >> 4;
        const float* wr = opw + o * 128;
        float acc = 0.f;
#pragma unroll 16
        for (int d2 = 0; d2 < 128; d2++) acc += v[p][d2] * wr[d2];
        x1s[p][o] = acc;
    }
    __syncthreads();
#pragma unroll
    for (int i = 0; i < 8; i++) {
        int id = i * 256 + t;
        int p = id & 15, j = id >> 4;
        const float* wr = f1w + j * 64;
        float acc = f1b[j];
#pragma unroll 16
        for (int c = 0; c < 64; c++) acc += x1s[p][c] * wr[c];
        h1s[p][j] = silu(acc);
    }
    __syncthreads();
#pragma unroll
    for (int i = 0; i < 4; i++) {
        int id = i * 256 + t;
        int p = id & 15, o = id >> 4;
        const float* wr = f2w + o * 128;
        float acc = f2b[o];
#pragma unroll 16
        for (int j = 0; j < 128; j++) acc += h1s[p][j] * wr[j];
        out[((size_t)b * 64 + o) * cL + l0 + p] = acc + x1s[p][o];
    }
}

extern "C" void kernel_launch(void* const* d_in, const int* in_sizes, int n_in,
                              void* d_out, int out_size, void* d_ws, size_t ws_size,
                              hipStream_t stream) {
    (void)in_sizes; (void)n_in; (void)out_size; (void)ws_size;
    const float* x    = (const float*)d_in[0];
    const float* s0g  = (const float*)d_in[1];
    const float* s0b  = (const float*)d_in[2];
    const float* s0w  = (const float*)d_in[3];
    const float* s1g  = (const float*)d_in[4];
    const float* s1b  = (const float*)d_in[5];
    const float* s1w  = (const float*)d_in[6];
    const float* s2g  = (const float*)d_in[7];
    const float* s2b  = (const float*)d_in[8];
    const float* s2w  = (const float*)d_in[9];
    const float* s3g  = (const float*)d_in[10];
    const float* s3b  = (const float*)d_in[11];
    const float* s3w  = (const float*)d_in[12];
    const float* s4g  = (const float*)d_in[13];
    const float* s4b  = (const float*)d_in[14];
    const float* s4w  = (const float*)d_in[15];
    const float* cg   = (const float*)d_in[16];
    const float* cbb  = (const float*)d_in[17];
    const float* cw   = (const float*)d_in[18];
    const float* scg  = (const float*)d_in[19];
    const float* scb  = (const float*)d_in[20];
    const float* scw  = (const float*)d_in[21];
    const float* ipw  = (const float*)d_in[22];
    const float* dww  = (const float*)d_in[23];
    const float* dwb  = (const float*)d_in[24];
    const float* xpw  = (const float*)d_in[25];
    const float* dtw  = (const float*)d_in[26];
    const float* dtb  = (const float*)d_in[27];
    const float* Alog = (const float*)d_in[28];
    const float* Dsv  = (const float*)d_in[29];
    const float* lng  = (const float*)d_in[30];
    const float* lnb  = (const float*)d_in[31];
    const float* opw  = (const float*)d_in[32];
    const float* f1w  = (const float*)d_in[33];
    const float* f1b  = (const float*)d_in[34];
    const float* f2w  = (const float*)d_in[35];
    const float* f2b  = (const float*)d_in[36];
    float* out = (float*)d_out;

    float* ws = (float*)d_ws;
    size_t off = 0;
    // --- region A: everything here is dead before k_xdbl4; delta overlays [0, 2359296) ---
    float* pool3  = ws + off; off += 294912;   // cB*64*cL
    float* pool5  = ws + off; off += 73728;    // cB*64*576
    float* pool9  = ws + off; off += 18432;    // cB*64*144
    float* gmean  = ws + off; off += 128;      // cB*64
    float* c2cl   = ws + off; off += 147456;   // cB*576*128 (channel-last)
    float* c3cl   = ws + off; off += 36864;    // cB*144*128
    float* c4     = ws + off; off += 256;      // cB*128           -> 571776
    u16*   catbf  = (u16*)(ws + off); off += 1474560;  // cB*cL*640 u16 -> 2046336
    u16*   xbf    = (u16*)(ws + off); off += 147456;   // cB*cL*64 u16  -> 2193792
    u16*   w8     = (u16*)(ws + off); off += 186368;   // 64*KTOT u16   -> 2380160
    u16*   wcat   = (u16*)(ws + off); off += 8192;     // 2*128*64 u16  -> 2388352
    u16*   ipk    = (u16*)(ws + off); off += 8192;     // 256*64 u16    -> 2396544
    // delta overlay [0, 2359296) fits entirely inside region A (2396544) ✓
    float* xc     = ws + off; off += 589824;   // written k_ip, read k_dw
    u16*   xpk    = (u16*)(ws + off); off += 9216;     // 144*128 u16; read by k_xdbl4
    // --- live buffers (ws is 268 MB; no tight overlays needed below) ---
    float* xca    = ws + off; off += 589824;   // written k_dw, read k_xdbl4 + scans
    float* zbuf   = ws + off; off += 589824;   // written k_ip, read k_tail
    float* bcbuf  = ws + off; off += 589824;   // written k_xdbl4 (interleaved B/C), read scans
    float* Pend   = ws + off; off += 1048576;  // 4096*256
    float* hend   = ws + off; off += 1048576;  // 4096*256
    float* ybuf   = ws + off; off += 2359296;  // scan3 out / part overlay
    off += 294912;                             // pad: part needs 9*294912 = 2654208 <= ybuf+pad ✓
    // overlays
    float* delta  = ws + 0;    // (bk, p_spatial, 128), written k_xdbl4
    float* part   = ybuf;      // written k_comp, read k_ip; ybuf live from scan3

    k_setup<<<3296, 256, 0, stream>>>(x, pool3, pool5, pool9, gmean,
                                      cw, scw, s0w, s1w, ipw, xpw, w8, wcat, ipk, xpk);
    k_c1all<<<cB * 576 + cB * 144 + cB, 128, 0, stream>>>(pool5, pool9, gmean, s2g, s2b, s2w,
                                                          s3g, s3b, s3w, s4g, s4b, s4w, c2cl, c3cl, c4);
    k_cat2<<<cB * 144, 256, 0, stream>>>(x, pool3, c4, s0g, s0b, s1g, s1b, scg, scb, cg, cbb,
                                         wcat, c2cl, c3cl, catbf, xbf);
    k_comp<<<(cB * cL / 16) * 9, 64, 0, stream>>>(catbf, xbf, w8, part);
    k_ip<<<cB * cL / 16, 256, 0, stream>>>(part, ipk, xc, zbuf);
    k_dw<<<(cB * cL * 128 + 255) / 256, 256, 0, stream>>>(xc, dww, dwb, xca);
    k_xdbl4<<<cB * 144, 256, 0, stream>>>(xca, xpk, dtw, dtb, bcbuf, delta);
    k_scan1<<<64 * NCH, 256, 0, stream>>>(delta, xca, bcbuf, Alog, Pend, hend);
    k_scan2<<<64, 256, 0, stream>>>(Pend, hend);
    k_scan3<<<64 * NCH, 256, 0, stream>>>(delta, xca, bcbuf, Alog, Dsv, hend, ybuf);
    k_tail<<<cB * 144, 256, 0, stream>>>(ybuf, zbuf, lng, lnb, opw, f1w, f1b, f2w, f2b, out);
}